// Round 6
// baseline (285.851 us; speedup 1.0000x reference)
//
#include <hip/hip_runtime.h>
#include <hip/hip_cooperative_groups.h>

namespace cg = cooperative_groups;

typedef short s16x8 __attribute__((ext_vector_type(8)));
typedef float f32x4 __attribute__((ext_vector_type(4)));
typedef unsigned short u16;

#define BATCH 512
#define HD    1023
#define K0    2048
#define N0    2048
#define N1    1024
#define N2    512

#define SMEM_BYTES 133376  // max(head 133252, gemm1 82176, gemm2 57600)

// round-to-nearest-even f32 -> bf16 (inputs finite)
__device__ __forceinline__ u16 f2bf(float f) {
  unsigned u = __builtin_bit_cast(unsigned, f);
  unsigned r = (u + 0x7fffu + ((u >> 16) & 1u)) >> 16;
  return (u16)r;
}

__device__ __forceinline__ s16x8 pack8(f32x4 a, f32x4 b) {
  s16x8 r;
  r[0] = (short)f2bf(a[0]); r[1] = (short)f2bf(a[1]);
  r[2] = (short)f2bf(a[2]); r[3] = (short)f2bf(a[3]);
  r[4] = (short)f2bf(b[0]); r[5] = (short)f2bf(b[1]);
  r[6] = (short)f2bf(b[2]); r[7] = (short)f2bf(b[3]);
  return r;
}

// ================= phase A: gather (2 samples per block) =================
__device__ __forceinline__ void gather_phase(const int* __restrict__ pairs,
    const float* __restrict__ attrs, const float* __restrict__ h_drug,
    u16* __restrict__ xb) {
  const int s = 2 * blockIdx.x + (threadIdx.x >> 8);
  const int i0 = threadIdx.x & 255;
  const float* h0 = h_drug + (size_t)pairs[2 * s] * HD;
  const float* h1 = h_drug + (size_t)pairs[2 * s + 1] * HD;
  u16* xr = xb + (size_t)s * K0;
  for (int i = i0; i < HD; i += 256) {
    xr[i] = f2bf(h0[i]);
    xr[1024 + i] = f2bf(h1[i]);
  }
  if (i0 == 0) {
    xr[1023] = f2bf(attrs[4 * s + 1]);
    xr[2047] = f2bf(attrs[4 * s + 3]);
  }
}

// ================= phases B/C: split-K x2 MFMA GEMM =====================
// Y = relu(A[512 x 2048]bf16 * W[N x 2048]^T f32 + bias) -> bf16.
// Block = 2 sub-blocks (4 waves each); sub s handles K half s; LDS reduce.
// Tile 64 x BN; BK=64; LDS XOR-swizzle (T2); 4-deep reg prefetch; raw
// s_barrier + lgkmcnt(0) only in the loop (T4 discipline); setprio (T5).
#define GI(s, t) { \
  const size_t ab = (size_t)(t) * 128; const int wf = (t) * 64; \
  pa0_##s = *(const s16x8*)(agp0 + ab); \
  pa1_##s = *(const s16x8*)(agp1 + ab); \
  pw0_##s = *(const f32x4*)(wgp + wf); pw1_##s = *(const f32x4*)(wgp + wf + 4); \
  if constexpr (BN == 64) { \
    pw2_##s = *(const f32x4*)(wgp + wf + 8); pw3_##s = *(const f32x4*)(wgp + wf + 12); } }

#define GS(s, t, DOLOAD) { \
  char* buf = base + ((s) & 1) * BUFSZ; \
  *(s16x8*)(buf + awo0) = pa0_##s; \
  *(s16x8*)(buf + awo1) = pa1_##s; \
  *(s16x8*)(buf + 8192 + bwo0) = pack8(pw0_##s, pw1_##s); \
  if constexpr (BN == 64) *(s16x8*)(buf + 8192 + bwo1) = pack8(pw2_##s, pw3_##s); \
  asm volatile("s_waitcnt lgkmcnt(0)" ::: "memory"); \
  __builtin_amdgcn_s_barrier(); \
  asm volatile("" ::: "memory"); \
  if (DOLOAD) GI(s, (t) + 4) \
  __builtin_amdgcn_s_setprio(1); \
  _Pragma("unroll") \
  for (int ks = 0; ks < 2; ++ks) { \
    const int kq = ((ks << 6) | lk) ^ sw; \
    s16x8 a0 = *(const s16x8*)(buf + aoff + kq); \
    s16x8 a1 = *(const s16x8*)(buf + aoff + 2048 + kq); \
    s16x8 b0 = *(const s16x8*)(buf + 8192 + boff + kq); \
    acc00 = __builtin_amdgcn_mfma_f32_16x16x32_bf16(a0, b0, acc00, 0, 0, 0); \
    acc10 = __builtin_amdgcn_mfma_f32_16x16x32_bf16(a1, b0, acc10, 0, 0, 0); \
    if constexpr (BN == 64) { \
      s16x8 b1 = *(const s16x8*)(buf + 8192 + boff + 2048 + kq); \
      acc01 = __builtin_amdgcn_mfma_f32_16x16x32_bf16(a0, b1, acc01, 0, 0, 0); \
      acc11 = __builtin_amdgcn_mfma_f32_16x16x32_bf16(a1, b1, acc11, 0, 0, 0); \
    } \
  } \
  __builtin_amdgcn_s_setprio(0); }

template <int BN>
__device__ __forceinline__ void gemm_phase(char* smem,
    const u16* __restrict__ A, const float* __restrict__ W,
    const float* __restrict__ bias, u16* __restrict__ Y, int N) {
  constexpr int K = 2048;
  constexpr int BUFSZ = 8192 + BN * 128;
  const int tid = threadIdx.x;
  const int sub = tid >> 8;       // K-split half
  const int lt = tid & 255;       // local tid within sub-block
  const int lw = lt >> 6, l = lt & 63;
  const int wr = lw >> 1, wc = lw & 1;
  const int lrow = l & 15;
  const int lk = (l >> 4) << 4;
  const int sw = (lrow & 7) << 4;

  // XCD-aware swizzle: 8 XCDs x contiguous chunk of 32 wgids (4 bn x 8 bm)
  const int wgid = ((blockIdx.x & 7) << 5) + (blockIdx.x >> 3);
  const int bn = wgid >> 3, bm = wgid & 7;

  const size_t K2 = (size_t)K * 2;
  const char* Ag = (const char*)A + (size_t)bm * 64 * K2 + (size_t)sub * 2048;
  const float* Wg = W + (size_t)bn * BN * K + sub * 1024;

  // A staging: 64 rows x 128 B bf16; thread covers bytes lt*16 and +4096
  const int o0 = lt * 16;
  const int ar0 = o0 >> 7, ac0 = o0 & 127;
  const char* agp0 = Ag + (size_t)ar0 * K2 + ac0;
  const int awo0 = (ar0 << 7) + (ac0 ^ ((ar0 & 7) << 4));
  const int o1 = o0 + 4096;
  const int ar1 = o1 >> 7, ac1 = o1 & 127;
  const char* agp1 = Ag + (size_t)ar1 * K2 + ac1;
  const int awo1 = (ar1 << 7) + (ac1 ^ ((ar1 & 7) << 4));

  // W staging (f32 -> bf16): BN=64: 16 floats/thread; BN=32: 8 floats/thread
  const int br = (BN == 64) ? (lt >> 2) : (lt >> 3);
  const int bq = (BN == 64) ? (lt & 3) : (lt & 7);
  const float* wgp = Wg + (size_t)br * K + bq * ((BN == 64) ? 16 : 8);
  const int bsw = (br & 7) << 4;
  const int bwo0 = (br << 7) + (((BN == 64) ? bq * 32 : bq * 16) ^ bsw);
  const int bwo1 = (br << 7) + ((bq * 32 + 16) ^ bsw);  // BN==64 only

  const int aoff = (wr * 32 + lrow) * 128;
  const int boff = (((BN == 64) ? wc * 32 : wc * 16) + lrow) * 128;

  char* base = smem + sub * 2 * BUFSZ;

  f32x4 acc00 = {}, acc01 = {}, acc10 = {}, acc11 = {};
  s16x8 pa0_0, pa0_1, pa0_2, pa0_3;
  s16x8 pa1_0, pa1_1, pa1_2, pa1_3;
  f32x4 pw0_0, pw1_0, pw2_0, pw3_0;
  f32x4 pw0_1, pw1_1, pw2_1, pw3_1;
  f32x4 pw0_2, pw1_2, pw2_2, pw3_2;
  f32x4 pw0_3, pw1_3, pw2_3, pw3_3;

  GI(0, 0) GI(1, 1) GI(2, 2) GI(3, 3)
  constexpr int NT = 16;  // K/2 / 64
  int t = 0;
  for (; t < NT - 4; t += 4) {
    GS(0, t, 1) GS(1, t + 1, 1) GS(2, t + 2, 1) GS(3, t + 3, 1)
  }
  GS(0, t, 0) GS(1, t + 1, 0) GS(2, t + 2, 0) GS(3, t + 3, 0)

  // split-K reduce through LDS, then bias+relu+store (sub 0 finishes)
  constexpr int RP = BN + 1;
  float* red = (float*)(smem + 4 * BUFSZ);
  const int rcol = ((BN == 64) ? wc * 32 : wc * 16) + lrow;
  if (sub == 1) {
#pragma unroll
    for (int fa = 0; fa < 2; ++fa)
#pragma unroll
      for (int r = 0; r < 4; ++r) {
        const int row = wr * 32 + fa * 16 + ((l >> 4) << 2) + r;
        red[row * RP + rcol] = (fa ? acc10 : acc00)[r];
        if constexpr (BN == 64) red[row * RP + rcol + 16] = (fa ? acc11 : acc01)[r];
      }
  }
  __syncthreads();
  if (sub == 0) {
    const int colg = bn * BN + rcol;
    const float bv0 = bias[colg];
    float bv1 = 0.f;
    if constexpr (BN == 64) bv1 = bias[colg + 16];
#pragma unroll
    for (int fa = 0; fa < 2; ++fa)
#pragma unroll
      for (int r = 0; r < 4; ++r) {
        const int row = wr * 32 + fa * 16 + ((l >> 4) << 2) + r;
        const int rowg = bm * 64 + row;
        float v = (fa ? acc10 : acc00)[r] + red[row * RP + rcol] + bv0;
        v = v > 0.f ? v : 0.f;
        Y[(size_t)rowg * N + colg] = f2bf(v);
        if constexpr (BN == 64) {
          float v2 = (fa ? acc11 : acc01)[r] + red[row * RP + rcol + 16] + bv1;
          v2 = v2 > 0.f ? v2 : 0.f;
          Y[(size_t)rowg * N + colg + 16] = f2bf(v2);
        }
      }
  }
}

// ================= phase D: head (cell,row-tile) MFMA ====================
#define H_ISSUE(S, ch) { \
  const float* src = hsrc + (ch) * 256; \
  q0_##S = *(const f32x4*)(src);      q1_##S = *(const f32x4*)(src + 4); \
  q2_##S = *(const f32x4*)(src + 8);  q3_##S = *(const f32x4*)(src + 12); \
  q4_##S = *(const f32x4*)(src + 16); q5_##S = *(const f32x4*)(src + 20); \
  q6_##S = *(const f32x4*)(src + 24); q7_##S = *(const f32x4*)(src + 28); }

#define H_WRITE(S, ch) { \
  char* dst = (((ch) & 1) ? lb1 : lb0) + (hrow << 9); \
  *(s16x8*)(dst + ((hcb + 0)  ^ hswz)) = pack8(q0_##S, q1_##S); \
  *(s16x8*)(dst + ((hcb + 16) ^ hswz)) = pack8(q2_##S, q3_##S); \
  *(s16x8*)(dst + ((hcb + 32) ^ hswz)) = pack8(q4_##S, q5_##S); \
  *(s16x8*)(dst + ((hcb + 48) ^ hswz)) = pack8(q6_##S, q7_##S); }

#define H_SYNC { \
  asm volatile("s_waitcnt lgkmcnt(0)" ::: "memory"); \
  __builtin_amdgcn_s_barrier(); \
  asm volatile("" ::: "memory"); }

// acc is a true array with compile-time indices only (stays in VGPRs).
#define H_MFMA(ch) { \
  const char* bb = ((ch) & 1) ? lb1 : lb0; \
  s16x8 bv0 = *(const s16x8*)(bb + ((0 * 16 + lrow) << 9) + kboff); \
  s16x8 bv1 = *(const s16x8*)(bb + ((1 * 16 + lrow) << 9) + kboff); \
  s16x8 bv2 = *(const s16x8*)(bb + ((2 * 16 + lrow) << 9) + kboff); \
  s16x8 bv3 = *(const s16x8*)(bb + ((3 * 16 + lrow) << 9) + kboff); \
  s16x8 av0 = *(const s16x8*)(ap0 + (ch) * 256); \
  s16x8 av1 = *(const s16x8*)(ap1 + (ch) * 256); \
  __builtin_amdgcn_s_setprio(1); \
  acc[0][0] = __builtin_amdgcn_mfma_f32_16x16x32_bf16(av0, bv0, acc[0][0], 0, 0, 0); \
  acc[0][1] = __builtin_amdgcn_mfma_f32_16x16x32_bf16(av0, bv1, acc[0][1], 0, 0, 0); \
  acc[0][2] = __builtin_amdgcn_mfma_f32_16x16x32_bf16(av0, bv2, acc[0][2], 0, 0, 0); \
  acc[0][3] = __builtin_amdgcn_mfma_f32_16x16x32_bf16(av0, bv3, acc[0][3], 0, 0, 0); \
  acc[1][0] = __builtin_amdgcn_mfma_f32_16x16x32_bf16(av1, bv0, acc[1][0], 0, 0, 0); \
  acc[1][1] = __builtin_amdgcn_mfma_f32_16x16x32_bf16(av1, bv1, acc[1][1], 0, 0, 0); \
  acc[1][2] = __builtin_amdgcn_mfma_f32_16x16x32_bf16(av1, bv2, acc[1][2], 0, 0, 0); \
  acc[1][3] = __builtin_amdgcn_mfma_f32_16x16x32_bf16(av1, bv3, acc[1][3], 0, 0, 0); \
  __builtin_amdgcn_s_setprio(0); }

__device__ __forceinline__ void head_phase(char* smem,
    const int* __restrict__ cells, const u16* __restrict__ y2b,
    const float* __restrict__ L0, const float* __restrict__ O0,
    const float* __restrict__ L1, float* __restrict__ pp) {
  char* lb0 = smem;                        // 32 KB
  char* lb1 = smem + 32768;                // 32 KB
  float* red = (float*)(smem + 65536);     // 8 x 2048 f32 = 64 KB
  int* slist = (int*)(smem + 131072);      // 544 ints
  int* scnt = slist + 544;
  const int tid = threadIdx.x;
  const int c = blockIdx.x >> 3, rt = blockIdx.x & 7;
  if (tid == 0) *scnt = 0;
  __syncthreads();
  for (int i = tid; i < BATCH; i += 512)
    if (cells[i] == c) slist[atomicAdd(scnt, 1)] = i;
  __syncthreads();
  const int ns = *scnt;
  if (ns > 0) {
    const int npad = (ns + 31) & ~31;
    for (int i = ns + tid; i < npad; i += 512) slist[i] = slist[0];
    __syncthreads();

    const int w = tid >> 6, l = tid & 63;
    const int lrow = l & 15;
    const int r0 = rt * 64;
    const float* L0c = L0 + ((size_t)c * N2 + r0) * N1;
    const int hrow = tid >> 3;
    const int hcb = (tid & 7) * 64;
    const int hswz = (hrow & 7) << 4;
    const float* hsrc = L0c + (size_t)hrow * N1 + (tid & 7) * 32;
    const int kboff = ((w * 64 + ((l >> 4) << 4)) ^ ((lrow & 7) << 4));

    f32x4 q0_A, q1_A, q2_A, q3_A, q4_A, q5_A, q6_A, q7_A;
    f32x4 q0_B, q1_B, q2_B, q3_B, q4_B, q5_B, q6_B, q7_B;

    for (int cb = 0; cb < npad; cb += 32) {
      const u16* ap0 = y2b + (size_t)slist[cb + lrow] * N1 + w * 32 + ((l >> 4) << 3);
      const u16* ap1 = y2b + (size_t)slist[cb + 16 + lrow] * N1 + w * 32 + ((l >> 4) << 3);
      f32x4 acc[2][4] = {};
      H_ISSUE(A, 0)
      H_WRITE(A, 0)
      H_ISSUE(B, 1)
      H_SYNC
      H_MFMA(0)
      H_WRITE(B, 1)
      H_ISSUE(A, 2)
      H_SYNC
      H_MFMA(1)
      H_WRITE(A, 2)
      H_ISSUE(B, 3)
      H_SYNC
      H_MFMA(2)
      H_WRITE(B, 3)
      H_SYNC
      H_MFMA(3)

      __syncthreads();
#pragma unroll
      for (int h = 0; h < 2; ++h)
#pragma unroll
        for (int fb = 0; fb < 4; ++fb)
#pragma unroll
          for (int r = 0; r < 4; ++r) {
            const int s0 = h * 16 + (l >> 4) * 4 + r;
            red[w * 2048 + s0 * 64 + fb * 16 + lrow] = acc[h][fb][r];
          }
      __syncthreads();
      {
        const int s = tid >> 4;
        const int rq = (tid & 15) * 4;
        if (cb + s < ns) {
          float p = 0.f;
#pragma unroll
          for (int j = 0; j < 4; ++j) {
            const int r = rq + j, e = s * 64 + r;
            float v = red[e] + red[2048 + e] + red[4096 + e] + red[6144 + e] +
                      red[8192 + e] + red[10240 + e] + red[12288 + e] + red[14336 + e] +
                      O0[(size_t)c * N2 + r0 + r];
            v = v > 0.f ? v : 0.f;
            p += v * L1[(size_t)c * N2 + r0 + r];
          }
#pragma unroll
          for (int off = 8; off; off >>= 1) p += __shfl_xor(p, off, 16);
          if ((tid & 15) == 0) pp[(size_t)rt * BATCH + slist[cb + s]] = p;
        }
      }
    }
  }
}

// ================= fused cooperative kernel =============================
__global__ __launch_bounds__(512, 1) void k_fused(
    const int* pairs, const int* cells, const float* attrs, const float* h_drug,
    const float* W0, const float* b0, const float* W1, const float* b1,
    const float* L0, const float* O0, const float* L1, const float* O1,
    float* out, u16* xb, u16* y1b, u16* y2b, float* pp) {
  __shared__ char smem[SMEM_BYTES];
  cg::grid_group grid = cg::this_grid();

  gather_phase(pairs, attrs, h_drug, xb);
  grid.sync();
  __threadfence();  // defensive: agent-scope acquire (cross-XCD L2)
  gemm_phase<64>(smem, xb, W0, b0, y1b, N0);
  grid.sync();
  __threadfence();
  gemm_phase<32>(smem, y1b, W1, b1, y2b, N1);
  grid.sync();
  __threadfence();
  head_phase(smem, cells, y2b, L0, O0, L1, pp);
  grid.sync();
  __threadfence();
  if (blockIdx.x == 0) {
    const int b = threadIdx.x;
    float s = O1[cells[b]];
#pragma unroll
    for (int rt = 0; rt < 8; ++rt) s += pp[(size_t)rt * BATCH + b];
    out[b] = s;
  }
}

// ================= launch ==============================================
extern "C" void kernel_launch(void* const* d_in, const int* in_sizes, int n_in,
                              void* d_out, int out_size, void* d_ws, size_t ws_size,
                              hipStream_t stream) {
  const int*   pairs  = (const int*)d_in[0];
  const int*   cells  = (const int*)d_in[1];
  const float* attrs  = (const float*)d_in[2];
  const float* h_drug = (const float*)d_in[3];
  const float* W0     = (const float*)d_in[4];
  const float* b0     = (const float*)d_in[5];
  const float* W1     = (const float*)d_in[6];
  const float* b1     = (const float*)d_in[7];
  const float* L0     = (const float*)d_in[8];
  const float* O0     = (const float*)d_in[9];
  const float* L1     = (const float*)d_in[10];
  const float* O1     = (const float*)d_in[11];
  float* out = (float*)d_out;

  char* ws = (char*)d_ws;
  u16*   xb  = (u16*)(ws);                 // 2 MB  512x2048 bf16
  u16*   y1b = (u16*)(ws + (2u << 20));    // 2 MB  512x2048 bf16
  u16*   y2b = (u16*)(ws + (4u << 20));    // 1 MB  512x1024 bf16
  float* pp  = (float*)(ws + (5u << 20));  // 16 KB 8x512 f32

  void* args[] = {
    (void*)&pairs, (void*)&cells, (void*)&attrs, (void*)&h_drug,
    (void*)&W0, (void*)&b0, (void*)&W1, (void*)&b1,
    (void*)&L0, (void*)&O0, (void*)&L1, (void*)&O1,
    (void*)&out, (void*)&xb, (void*)&y1b, (void*)&y2b, (void*)&pp
  };
  hipLaunchCooperativeKernel((void*)k_fused, dim3(256), dim3(512), args, 0, stream);
}

// Round 7
// 52.975 us; speedup vs baseline: 5.3959x; 5.3959x over previous
//
#include <hip/hip_runtime.h>

typedef short s16x8 __attribute__((ext_vector_type(8)));
typedef float f32x4 __attribute__((ext_vector_type(4)));
typedef unsigned short u16;

#define BATCH 512
#define HD    1023
#define K0    2048
#define N0    2048
#define N1    1024
#define N2    512

// round-to-nearest-even f32 -> bf16 (inputs finite)
__device__ __forceinline__ u16 f2bf(float f) {
  unsigned u = __builtin_bit_cast(unsigned, f);
  unsigned r = (u + 0x7fffu + ((u >> 16) & 1u)) >> 16;
  return (u16)r;
}

__device__ __forceinline__ s16x8 pack8(f32x4 a, f32x4 b) {
  s16x8 r;
  r[0] = (short)f2bf(a[0]); r[1] = (short)f2bf(a[1]);
  r[2] = (short)f2bf(a[2]); r[3] = (short)f2bf(a[3]);
  r[4] = (short)f2bf(b[0]); r[5] = (short)f2bf(b[1]);
  r[6] = (short)f2bf(b[2]); r[7] = (short)f2bf(b[3]);
  return r;
}

// ---------------- gather: build bf16 x[512][2048] ----------------
__global__ __launch_bounds__(256) void k_gather(const int* __restrict__ pairs,
    const float* __restrict__ attrs, const float* __restrict__ h_drug,
    u16* __restrict__ xb) {
  int b = blockIdx.x;
  const float* h0 = h_drug + (size_t)pairs[2 * b] * HD;
  const float* h1 = h_drug + (size_t)pairs[2 * b + 1] * HD;
  u16* xr = xb + (size_t)b * K0;
  for (int i = threadIdx.x; i < HD; i += 256) {
    xr[i] = f2bf(h0[i]);
    xr[1024 + i] = f2bf(h1[i]);
  }
  if (threadIdx.x == 0) {
    xr[1023] = f2bf(attrs[4 * b + 1]);
    xr[2047] = f2bf(attrs[4 * b + 3]);
  }
}

// ---------------- bf16 MFMA GEMM, fused W f32->bf16, 4-deep prefetch ----------
// Y = relu(A[512 x 2048]bf16 * W[N x 2048]^T f32 + bias) -> bf16.
// Block tile BM x 32, BK=64, 4 waves 2x2 (wave tile (BM/2) x 16).
// Grid 512 = 2 blocks/CU for barrier-stall overlap. T2 swizzle, T4 discipline.
#define GI(s, t) { \
  const size_t ab = (size_t)(t) * 128; const int wf = (t) * 64; \
  pa0_##s = *(const s16x8*)(agp0 + ab); \
  if constexpr (AF == 2) pa1_##s = *(const s16x8*)(agp1 + ab); \
  pw0_##s = *(const f32x4*)(wgp + wf); pw1_##s = *(const f32x4*)(wgp + wf + 4); }

#define GS(s, t, DOLOAD) { \
  char* buf = lds[(s) & 1]; \
  *(s16x8*)(buf + awo0) = pa0_##s; \
  if constexpr (AF == 2) *(s16x8*)(buf + awo1) = pa1_##s; \
  *(s16x8*)(buf + ABYTES + bwo0) = pack8(pw0_##s, pw1_##s); \
  asm volatile("s_waitcnt lgkmcnt(0)" ::: "memory"); \
  __builtin_amdgcn_s_barrier(); \
  asm volatile("" ::: "memory"); \
  if (DOLOAD) GI(s, (t) + 4) \
  __builtin_amdgcn_s_setprio(1); \
  _Pragma("unroll") \
  for (int ks = 0; ks < 2; ++ks) { \
    const int kq = ((ks << 6) | lk) ^ sw; \
    s16x8 a0 = *(const s16x8*)(buf + aoff + kq); \
    s16x8 b0 = *(const s16x8*)(buf + ABYTES + boff + kq); \
    acc0 = __builtin_amdgcn_mfma_f32_16x16x32_bf16(a0, b0, acc0, 0, 0, 0); \
    if constexpr (AF == 2) { \
      s16x8 a1 = *(const s16x8*)(buf + aoff + 2048 + kq); \
      acc1 = __builtin_amdgcn_mfma_f32_16x16x32_bf16(a1, b0, acc1, 0, 0, 0); \
    } \
  } \
  __builtin_amdgcn_s_setprio(0); }

template <int BM>
__global__ __launch_bounds__(256) void k_gemm(
    const u16* __restrict__ A, const float* __restrict__ W,
    const float* __restrict__ bias, u16* __restrict__ Y, int N) {
  constexpr int K = 2048;
  constexpr int AF = BM / 32;            // A fragments per wave (1 or 2)
  constexpr int ABYTES = BM * 128;       // A tile bytes (bf16, 64 k)
  constexpr int NBMSH = (BM == 64) ? 3 : 4;   // log2(M/BM)
  __shared__ char lds[2][ABYTES + 4096];
  const int tid = threadIdx.x;
  const int w = tid >> 6, l = tid & 63;
  const int wr = w >> 1, wc = w & 1;
  const int lrow = l & 15;
  const int lk = (l >> 4) << 4;
  const int sw = (lrow & 7) << 4;

  // XCD-aware swizzle (grid=512): each XCD owns a contiguous 64-wgid chunk
  const int wgid = (blockIdx.x & 7) * 64 + (blockIdx.x >> 3);
  const int bn = wgid >> NBMSH, bm = wgid & ((1 << NBMSH) - 1);

  const size_t K2 = (size_t)K * 2;
  const char* Ag = (const char*)A + (size_t)bm * BM * K2;
  const float* Wg = W + (size_t)bn * 32 * K;

  // A staging map (bf16 copy, 16B/slot); BM==64 has a second slot at +4096
  const int o0 = tid * 16;
  const int ar0 = o0 >> 7, ac0 = o0 & 127;
  const char* agp0 = Ag + (size_t)ar0 * K2 + ac0;
  const int awo0 = (ar0 << 7) + (ac0 ^ ((ar0 & 7) << 4));
  const int o1 = o0 + 4096;
  const int ar1 = o1 >> 7, ac1 = o1 & 127;
  const char* agp1 = Ag + (size_t)ar1 * K2 + ac1;   // used only if AF==2
  const int awo1 = (ar1 << 7) + (ac1 ^ ((ar1 & 7) << 4));

  // W staging (f32 -> bf16): row tid>>3 (0..31), 8 floats at (tid&7)*8
  const int br = tid >> 3, bq = tid & 7;
  const float* wgp = Wg + (size_t)br * K + bq * 8;
  const int bwo0 = (br << 7) + ((bq * 16) ^ ((br & 7) << 4));

  const int aoff = (wr * (BM / 2) + lrow) * 128;
  const int boff = (wc * 16 + lrow) * 128;

  f32x4 acc0 = {}, acc1 = {};
  s16x8 pa0_0, pa0_1, pa0_2, pa0_3;
  s16x8 pa1_0, pa1_1, pa1_2, pa1_3;
  f32x4 pw0_0, pw1_0, pw0_1, pw1_1, pw0_2, pw1_2, pw0_3, pw1_3;

  GI(0, 0) GI(1, 1) GI(2, 2) GI(3, 3)
  constexpr int NT = 32;  // K/64
  int t = 0;
  for (; t < NT - 4; t += 4) {
    GS(0, t, 1) GS(1, t + 1, 1) GS(2, t + 2, 1) GS(3, t + 3, 1)
  }
  GS(0, t, 0) GS(1, t + 1, 0) GS(2, t + 2, 0) GS(3, t + 3, 0)

  // epilogue: C/D map col=lane&15, row=(lane>>4)*4+reg
  const int colg = bn * 32 + wc * 16 + lrow;
  const int rowb = bm * BM + wr * (BM / 2) + ((l >> 4) << 2);
  const float bv = bias[colg];
#pragma unroll
  for (int fa = 0; fa < AF; ++fa)
#pragma unroll
    for (int r = 0; r < 4; ++r) {
      float v = (fa ? acc1 : acc0)[r] + bv;
      v = v > 0.f ? v : 0.f;
      Y[(size_t)(rowb + fa * 16 + r) * N + colg] = f2bf(v);
    }
}

// ---------------- head: per (cell, 64-row tile); LDS-staged coalesced L0 ----------------
#define H_ISSUE(S, ch) { \
  const float* src = hsrc + (ch) * 256; \
  q0_##S = *(const f32x4*)(src);      q1_##S = *(const f32x4*)(src + 4); \
  q2_##S = *(const f32x4*)(src + 8);  q3_##S = *(const f32x4*)(src + 12); \
  q4_##S = *(const f32x4*)(src + 16); q5_##S = *(const f32x4*)(src + 20); \
  q6_##S = *(const f32x4*)(src + 24); q7_##S = *(const f32x4*)(src + 28); }

#define H_WRITE(S, ch) { \
  char* dst = lbuf[(ch) & 1] + (hrow << 9); \
  *(s16x8*)(dst + ((hcb + 0)  ^ hswz)) = pack8(q0_##S, q1_##S); \
  *(s16x8*)(dst + ((hcb + 16) ^ hswz)) = pack8(q2_##S, q3_##S); \
  *(s16x8*)(dst + ((hcb + 32) ^ hswz)) = pack8(q4_##S, q5_##S); \
  *(s16x8*)(dst + ((hcb + 48) ^ hswz)) = pack8(q6_##S, q7_##S); }

#define H_SYNC { \
  asm volatile("s_waitcnt lgkmcnt(0)" ::: "memory"); \
  __builtin_amdgcn_s_barrier(); \
  asm volatile("" ::: "memory"); }

#define H_MFMA(ch) { \
  const char* bb = lbuf[(ch) & 1]; \
  s16x8 bv0 = *(const s16x8*)(bb + ((0 * 16 + lrow) << 9) + kboff); \
  s16x8 bv1 = *(const s16x8*)(bb + ((1 * 16 + lrow) << 9) + kboff); \
  s16x8 bv2 = *(const s16x8*)(bb + ((2 * 16 + lrow) << 9) + kboff); \
  s16x8 bv3 = *(const s16x8*)(bb + ((3 * 16 + lrow) << 9) + kboff); \
  s16x8 av0 = *(const s16x8*)(ap0 + (ch) * 256); \
  s16x8 av1 = *(const s16x8*)(ap1 + (ch) * 256); \
  __builtin_amdgcn_s_setprio(1); \
  acc[0][0] = __builtin_amdgcn_mfma_f32_16x16x32_bf16(av0, bv0, acc[0][0], 0, 0, 0); \
  acc[0][1] = __builtin_amdgcn_mfma_f32_16x16x32_bf16(av0, bv1, acc[0][1], 0, 0, 0); \
  acc[0][2] = __builtin_amdgcn_mfma_f32_16x16x32_bf16(av0, bv2, acc[0][2], 0, 0, 0); \
  acc[0][3] = __builtin_amdgcn_mfma_f32_16x16x32_bf16(av0, bv3, acc[0][3], 0, 0, 0); \
  acc[1][0] = __builtin_amdgcn_mfma_f32_16x16x32_bf16(av1, bv0, acc[1][0], 0, 0, 0); \
  acc[1][1] = __builtin_amdgcn_mfma_f32_16x16x32_bf16(av1, bv1, acc[1][1], 0, 0, 0); \
  acc[1][2] = __builtin_amdgcn_mfma_f32_16x16x32_bf16(av1, bv2, acc[1][2], 0, 0, 0); \
  acc[1][3] = __builtin_amdgcn_mfma_f32_16x16x32_bf16(av1, bv3, acc[1][3], 0, 0, 0); \
  __builtin_amdgcn_s_setprio(0); }

__global__ __launch_bounds__(512) void k_head(
    const int* __restrict__ cells, const u16* __restrict__ y2b,
    const float* __restrict__ L0, const float* __restrict__ O0,
    const float* __restrict__ L1, float* __restrict__ pp) {
  __shared__ int slist[544];
  __shared__ int scnt;
  __shared__ float red[8][2048];      // 64 KB
  __shared__ char lbuf[2][32768];     // 64 KB: 64 rows x 512 B (bf16), XOR-swizzled
  const int tid = threadIdx.x;
  const int c = blockIdx.x >> 3, rt = blockIdx.x & 7;
  if (tid == 0) scnt = 0;
  __syncthreads();
  for (int i = tid; i < BATCH; i += 512)
    if (cells[i] == c) slist[atomicAdd(&scnt, 1)] = i;
  __syncthreads();
  const int ns = scnt;
  if (ns == 0) return;
  const int npad = (ns + 31) & ~31;
  for (int i = ns + tid; i < npad; i += 512) slist[i] = slist[0];
  __syncthreads();

  const int w = tid >> 6, l = tid & 63;
  const int lrow = l & 15;
  const int r0 = rt * 64;
  const float* L0c = L0 + ((size_t)c * N2 + r0) * N1;
  const int hrow = tid >> 3;
  const int hcb = (tid & 7) * 64;
  const int hswz = (hrow & 7) << 4;
  const float* hsrc = L0c + (size_t)hrow * N1 + (tid & 7) * 32;
  const int kboff = ((w * 64 + ((l >> 4) << 4)) ^ ((lrow & 7) << 4));

  f32x4 q0_A, q1_A, q2_A, q3_A, q4_A, q5_A, q6_A, q7_A;
  f32x4 q0_B, q1_B, q2_B, q3_B, q4_B, q5_B, q6_B, q7_B;

  for (int cb = 0; cb < npad; cb += 32) {
    const u16* ap0 = y2b + (size_t)slist[cb + lrow] * N1 + w * 32 + ((l >> 4) << 3);
    const u16* ap1 = y2b + (size_t)slist[cb + 16 + lrow] * N1 + w * 32 + ((l >> 4) << 3);
    f32x4 acc[2][4] = {};
    H_ISSUE(A, 0)
    H_WRITE(A, 0)
    H_ISSUE(B, 1)
    H_SYNC
    H_MFMA(0)
    H_WRITE(B, 1)
    H_ISSUE(A, 2)
    H_SYNC
    H_MFMA(1)
    H_WRITE(A, 2)
    H_ISSUE(B, 3)
    H_SYNC
    H_MFMA(2)
    H_WRITE(B, 3)
    H_SYNC
    H_MFMA(3)

    __syncthreads();
#pragma unroll
    for (int h = 0; h < 2; ++h)
#pragma unroll
      for (int fb = 0; fb < 4; ++fb)
#pragma unroll
        for (int r = 0; r < 4; ++r) {
          const int s0 = h * 16 + (l >> 4) * 4 + r;
          red[w][s0 * 64 + fb * 16 + lrow] = acc[h][fb][r];
        }
    __syncthreads();
    {
      const int s = tid >> 4;
      const int rq = (tid & 15) * 4;
      if (cb + s < ns) {
        float p = 0.f;
#pragma unroll
        for (int j = 0; j < 4; ++j) {
          const int r = rq + j, e = s * 64 + r;
          float v = red[0][e] + red[1][e] + red[2][e] + red[3][e] +
                    red[4][e] + red[5][e] + red[6][e] + red[7][e] +
                    O0[(size_t)c * N2 + r0 + r];
          v = v > 0.f ? v : 0.f;
          p += v * L1[(size_t)c * N2 + r0 + r];
        }
#pragma unroll
        for (int off = 8; off; off >>= 1) p += __shfl_xor(p, off, 16);
        if ((tid & 15) == 0) pp[(size_t)rt * BATCH + slist[cb + s]] = p;
      }
    }
  }
}

// ---------------- final: out[b] = sum_rt pp[rt][b] + O1[c] ----------------
__global__ __launch_bounds__(512) void k_final(
    const int* __restrict__ cells, const float* __restrict__ pp,
    const float* __restrict__ O1, float* __restrict__ out) {
  const int b = threadIdx.x;
  float s = O1[cells[b]];
#pragma unroll
  for (int rt = 0; rt < 8; ++rt) s += pp[(size_t)rt * BATCH + b];
  out[b] = s;
}

// ---------------- launch ----------------
extern "C" void kernel_launch(void* const* d_in, const int* in_sizes, int n_in,
                              void* d_out, int out_size, void* d_ws, size_t ws_size,
                              hipStream_t stream) {
  const int*   pairs  = (const int*)d_in[0];
  const int*   cells  = (const int*)d_in[1];
  const float* attrs  = (const float*)d_in[2];
  const float* h_drug = (const float*)d_in[3];
  const float* W0     = (const float*)d_in[4];
  const float* b0     = (const float*)d_in[5];
  const float* W1     = (const float*)d_in[6];
  const float* b1     = (const float*)d_in[7];
  const float* L0     = (const float*)d_in[8];
  const float* O0     = (const float*)d_in[9];
  const float* L1     = (const float*)d_in[10];
  const float* O1     = (const float*)d_in[11];
  float* out = (float*)d_out;

  char* ws = (char*)d_ws;
  u16*   xb  = (u16*)(ws);                 // 2 MB  512x2048 bf16
  u16*   y1b = (u16*)(ws + (2u << 20));    // 2 MB  512x2048 bf16
  u16*   y2b = (u16*)(ws + (4u << 20));    // 1 MB  512x1024 bf16
  float* pp  = (float*)(ws + (5u << 20));  // 16 KB 8x512 f32

  k_gather<<<BATCH, 256, 0, stream>>>(pairs, attrs, h_drug, xb);
  k_gemm<64><<<512, 256, 0, stream>>>(xb, W0, b0, y1b, N0);
  k_gemm<32><<<512, 256, 0, stream>>>(y1b, W1, b1, y2b, N1);
  k_head<<<256, 512, 0, stream>>>(cells, y2b, L0, O0, L1, pp);
  k_final<<<1, 512, 0, stream>>>(cells, pp, O1, out);
}

// Round 8
// 52.240 us; speedup vs baseline: 5.4718x; 1.0141x over previous
//
#include <hip/hip_runtime.h>

typedef short s16x8 __attribute__((ext_vector_type(8)));
typedef float f32x4 __attribute__((ext_vector_type(4)));
typedef unsigned short u16;

#define BATCH 512
#define HD    1023
#define K0    2048
#define N0    2048
#define N1    1024
#define N2    512

// round-to-nearest-even f32 -> bf16 (scalar path)
__device__ __forceinline__ u16 f2bf(float f) {
  unsigned u = __builtin_bit_cast(unsigned, f);
  unsigned r = (u + 0x7fffu + ((u >> 16) & 1u)) >> 16;
  return (u16)r;
}

// packed RNE convert: 8 f32 -> 8 bf16 in 4 VALU ops (T12 primitive)
__device__ __forceinline__ s16x8 pack8(f32x4 a, f32x4 b) {
  union { unsigned u[4]; s16x8 v; } r;
  asm("v_cvt_pk_bf16_f32 %0, %1, %2" : "=v"(r.u[0]) : "v"(a[0]), "v"(a[1]));
  asm("v_cvt_pk_bf16_f32 %0, %1, %2" : "=v"(r.u[1]) : "v"(a[2]), "v"(a[3]));
  asm("v_cvt_pk_bf16_f32 %0, %1, %2" : "=v"(r.u[2]) : "v"(b[0]), "v"(b[1]));
  asm("v_cvt_pk_bf16_f32 %0, %1, %2" : "=v"(r.u[3]) : "v"(b[2]), "v"(b[3]));
  return r.v;
}

// ---------------- gather: build bf16 x[512][2048]; init out[b]=O1[c] ----------------
__global__ __launch_bounds__(256) void k_gather(const int* __restrict__ pairs,
    const float* __restrict__ attrs, const float* __restrict__ h_drug,
    u16* __restrict__ xb, const int* __restrict__ cells,
    const float* __restrict__ O1, float* __restrict__ out) {
  int b = blockIdx.x;
  const float* h0 = h_drug + (size_t)pairs[2 * b] * HD;
  const float* h1 = h_drug + (size_t)pairs[2 * b + 1] * HD;
  u16* xr = xb + (size_t)b * K0;
  for (int i = threadIdx.x; i < HD; i += 256) {
    xr[i] = f2bf(h0[i]);
    xr[1024 + i] = f2bf(h1[i]);
  }
  if (threadIdx.x == 0) {
    xr[1023] = f2bf(attrs[4 * b + 1]);
    xr[2047] = f2bf(attrs[4 * b + 3]);
    out[b] = O1[cells[b]];  // head atomically accumulates onto this
  }
}

// ---------------- gemm1: splitK2, 64x64 tile, 2x2 wave frags ----------------
// P[sub] = A[512 x 2048]bf16(half-K) * W0[2048 x 2048]^T f32 -> f32 partials.
// 512 blocks (8 bm x 32 bn x 2 sub), 2 blocks/CU, 4-deep reg prefetch,
// T2 LDS swizzle, raw s_barrier + lgkmcnt(0) only (T4), setprio (T5).
#define GI1(s, t) { \
  const size_t ab = (size_t)(t) * 128; const int wf = (t) * 64; \
  pa0_##s = *(const s16x8*)(agp0 + ab); \
  pa1_##s = *(const s16x8*)(agp1 + ab); \
  pw0_##s = *(const f32x4*)(wgp + wf);     pw1_##s = *(const f32x4*)(wgp + wf + 4); \
  pw2_##s = *(const f32x4*)(wgp + wf + 8); pw3_##s = *(const f32x4*)(wgp + wf + 12); }

#define GS1(s, t, DOLOAD) { \
  char* buf = lds[(s) & 1]; \
  *(s16x8*)(buf + awo0) = pa0_##s; \
  *(s16x8*)(buf + awo1) = pa1_##s; \
  *(s16x8*)(buf + 8192 + bwo0) = pack8(pw0_##s, pw1_##s); \
  *(s16x8*)(buf + 8192 + bwo1) = pack8(pw2_##s, pw3_##s); \
  asm volatile("s_waitcnt lgkmcnt(0)" ::: "memory"); \
  __builtin_amdgcn_s_barrier(); \
  asm volatile("" ::: "memory"); \
  if (DOLOAD) GI1(s, (t) + 4) \
  __builtin_amdgcn_s_setprio(1); \
  _Pragma("unroll") \
  for (int ks = 0; ks < 2; ++ks) { \
    const int kq = ((ks << 6) | lk) ^ sw; \
    s16x8 a0 = *(const s16x8*)(buf + aoff + kq); \
    s16x8 a1 = *(const s16x8*)(buf + aoff + 2048 + kq); \
    s16x8 b0 = *(const s16x8*)(buf + 8192 + boff + kq); \
    s16x8 b1 = *(const s16x8*)(buf + 8192 + boff + 2048 + kq); \
    acc00 = __builtin_amdgcn_mfma_f32_16x16x32_bf16(a0, b0, acc00, 0, 0, 0); \
    acc01 = __builtin_amdgcn_mfma_f32_16x16x32_bf16(a0, b1, acc01, 0, 0, 0); \
    acc10 = __builtin_amdgcn_mfma_f32_16x16x32_bf16(a1, b0, acc10, 0, 0, 0); \
    acc11 = __builtin_amdgcn_mfma_f32_16x16x32_bf16(a1, b1, acc11, 0, 0, 0); \
  } \
  __builtin_amdgcn_s_setprio(0); }

__global__ __launch_bounds__(256) void k_gemm1(
    const u16* __restrict__ A, const float* __restrict__ W,
    float* __restrict__ P) {
  constexpr int K = 2048, N = 2048;
  __shared__ char lds[2][16384];  // A 8KB + B 8KB per buffer
  const int tid = threadIdx.x;
  const int w = tid >> 6, l = tid & 63;
  const int wr = w >> 1, wc = w & 1;
  const int lrow = l & 15;
  const int lk = (l >> 4) << 4;
  const int sw = (lrow & 7) << 4;

  // XCD swizzle: each XCD owns 64 contiguous wgids = 4 bn panels x 8 bm x 2 sub
  const int wgid = (blockIdx.x & 7) * 64 + (blockIdx.x >> 3);
  const int bn = wgid >> 4;          // 0..31
  const int bm = (wgid >> 1) & 7;    // 0..7
  const int sub = wgid & 1;          // K half

  const size_t K2 = (size_t)K * 2;
  const char* Ag = (const char*)A + (size_t)bm * 64 * K2 + (size_t)sub * 2048;
  const float* Wg = W + (size_t)bn * 64 * K + sub * 1024;

  // A staging: 64 rows x 128B bf16; thread covers tile bytes tid*16 and +4096
  const int o0 = tid * 16;
  const int ar0 = o0 >> 7, ac0 = o0 & 127;
  const char* agp0 = Ag + (size_t)ar0 * K2 + ac0;
  const int awo0 = (ar0 << 7) + (ac0 ^ ((ar0 & 7) << 4));
  const int o1 = o0 + 4096;
  const int ar1 = o1 >> 7, ac1 = o1 & 127;
  const char* agp1 = Ag + (size_t)ar1 * K2 + ac1;
  const int awo1 = (ar1 << 7) + (ac1 ^ ((ar1 & 7) << 4));

  // W staging (f32 -> bf16): row tid>>2 (0..63), 16 floats at (tid&3)*16
  const int br = tid >> 2, bq = tid & 3;
  const float* wgp = Wg + (size_t)br * K + bq * 16;
  const int bsw = (br & 7) << 4;
  const int bwo0 = (br << 7) + ((bq * 32) ^ bsw);
  const int bwo1 = (br << 7) + ((bq * 32 + 16) ^ bsw);

  const int aoff = (wr * 32 + lrow) * 128;
  const int boff = (wc * 32 + lrow) * 128;

  f32x4 acc00 = {}, acc01 = {}, acc10 = {}, acc11 = {};
  s16x8 pa0_0, pa0_1, pa0_2, pa0_3;
  s16x8 pa1_0, pa1_1, pa1_2, pa1_3;
  f32x4 pw0_0, pw1_0, pw2_0, pw3_0;
  f32x4 pw0_1, pw1_1, pw2_1, pw3_1;
  f32x4 pw0_2, pw1_2, pw2_2, pw3_2;
  f32x4 pw0_3, pw1_3, pw2_3, pw3_3;

  GI1(0, 0) GI1(1, 1) GI1(2, 2) GI1(3, 3)
  constexpr int NT = 16;  // (K/2)/64
  int t = 0;
  for (; t < NT - 4; t += 4) {
    GS1(0, t, 1) GS1(1, t + 1, 1) GS1(2, t + 2, 1) GS1(3, t + 3, 1)
  }
  GS1(0, t, 0) GS1(1, t + 1, 0) GS1(2, t + 2, 0) GS1(3, t + 3, 0)

  // store f32 partials (no bias/relu yet)
  float* Pp = P + (size_t)sub * (BATCH * (size_t)N);
  const int colg = bn * 64 + wc * 32 + lrow;
  const int rowg = bm * 64 + wr * 32 + ((l >> 4) << 2);
#pragma unroll
  for (int r = 0; r < 4; ++r) {
    Pp[(size_t)(rowg + r) * N + colg]           = acc00[r];
    Pp[(size_t)(rowg + r) * N + colg + 16]      = acc01[r];
    Pp[(size_t)(rowg + 16 + r) * N + colg]      = acc10[r];
    Pp[(size_t)(rowg + 16 + r) * N + colg + 16] = acc11[r];
  }
}

// ---------------- red1: y1 = relu(P0 + P1 + b0) -> bf16 ----------------
__global__ __launch_bounds__(256) void k_red1(
    const float* __restrict__ P, const float* __restrict__ bias,
    u16* __restrict__ Y) {
  const int i = blockIdx.x * 256 + threadIdx.x;  // 131072 threads x 8 elems
  const size_t e = (size_t)i * 8;
  const int col = (int)(e & 2047);
  f32x4 a0 = *(const f32x4*)(P + e);
  f32x4 a1 = *(const f32x4*)(P + e + 4);
  f32x4 c0 = *(const f32x4*)(P + (size_t)BATCH * N0 + e);
  f32x4 c1 = *(const f32x4*)(P + (size_t)BATCH * N0 + e + 4);
  f32x4 d0 = *(const f32x4*)(bias + col);
  f32x4 d1 = *(const f32x4*)(bias + col + 4);
#pragma unroll
  for (int j = 0; j < 4; ++j) {
    float v0 = a0[j] + c0[j] + d0[j];
    float v1 = a1[j] + c1[j] + d1[j];
    a0[j] = v0 > 0.f ? v0 : 0.f;
    a1[j] = v1 > 0.f ? v1 : 0.f;
  }
  *(s16x8*)(Y + e) = pack8(a0, a1);
}

// ---------------- gemm2: BM=32 x BN=32 tile, grid 512 (v7 structure) ----------
#define GI(s, t) { \
  const size_t ab = (size_t)(t) * 128; const int wf = (t) * 64; \
  pa0_##s = *(const s16x8*)(agp0 + ab); \
  pw0_##s = *(const f32x4*)(wgp + wf); pw1_##s = *(const f32x4*)(wgp + wf + 4); }

#define GS(s, t, DOLOAD) { \
  char* buf = lds[(s) & 1]; \
  *(s16x8*)(buf + awo0) = pa0_##s; \
  *(s16x8*)(buf + ABYTES + bwo0) = pack8(pw0_##s, pw1_##s); \
  asm volatile("s_waitcnt lgkmcnt(0)" ::: "memory"); \
  __builtin_amdgcn_s_barrier(); \
  asm volatile("" ::: "memory"); \
  if (DOLOAD) GI(s, (t) + 4) \
  __builtin_amdgcn_s_setprio(1); \
  _Pragma("unroll") \
  for (int ks = 0; ks < 2; ++ks) { \
    const int kq = ((ks << 6) | lk) ^ sw; \
    s16x8 a0 = *(const s16x8*)(buf + aoff + kq); \
    s16x8 b0 = *(const s16x8*)(buf + ABYTES + boff + kq); \
    acc0 = __builtin_amdgcn_mfma_f32_16x16x32_bf16(a0, b0, acc0, 0, 0, 0); \
  } \
  __builtin_amdgcn_s_setprio(0); }

__global__ __launch_bounds__(256) void k_gemm2(
    const u16* __restrict__ A, const float* __restrict__ W,
    const float* __restrict__ bias, u16* __restrict__ Y) {
  constexpr int K = 2048, N = 1024;
  constexpr int ABYTES = 32 * 128;
  __shared__ char lds[2][ABYTES + 4096];
  const int tid = threadIdx.x;
  const int w = tid >> 6, l = tid & 63;
  const int wr = w >> 1, wc = w & 1;
  const int lrow = l & 15;
  const int lk = (l >> 4) << 4;
  const int sw = (lrow & 7) << 4;

  const int wgid = (blockIdx.x & 7) * 64 + (blockIdx.x >> 3);
  const int bn = wgid >> 4, bm = wgid & 15;

  const size_t K2 = (size_t)K * 2;
  const char* Ag = (const char*)A + (size_t)bm * 32 * K2;
  const float* Wg = W + (size_t)bn * 32 * K;

  const int o0 = tid * 16;
  const int ar0 = o0 >> 7, ac0 = o0 & 127;
  const char* agp0 = Ag + (size_t)ar0 * K2 + ac0;
  const int awo0 = (ar0 << 7) + (ac0 ^ ((ar0 & 7) << 4));

  const int br = tid >> 3, bq = tid & 7;
  const float* wgp = Wg + (size_t)br * K + bq * 8;
  const int bwo0 = (br << 7) + ((bq * 16) ^ ((br & 7) << 4));

  const int aoff = (wr * 16 + lrow) * 128;
  const int boff = (wc * 16 + lrow) * 128;

  f32x4 acc0 = {};
  s16x8 pa0_0, pa0_1, pa0_2, pa0_3;
  f32x4 pw0_0, pw1_0, pw0_1, pw1_1, pw0_2, pw1_2, pw0_3, pw1_3;

  GI(0, 0) GI(1, 1) GI(2, 2) GI(3, 3)
  constexpr int NT = 32;
  int t = 0;
  for (; t < NT - 4; t += 4) {
    GS(0, t, 1) GS(1, t + 1, 1) GS(2, t + 2, 1) GS(3, t + 3, 1)
  }
  GS(0, t, 0) GS(1, t + 1, 0) GS(2, t + 2, 0) GS(3, t + 3, 0)

  const int colg = bn * 32 + wc * 16 + lrow;
  const int rowb = bm * 32 + wr * 16 + ((l >> 4) << 2);
  const float bv = bias[colg];
#pragma unroll
  for (int r = 0; r < 4; ++r) {
    float v = acc0[r] + bv;
    v = v > 0.f ? v : 0.f;
    Y[(size_t)(rowb + r) * N + colg] = f2bf(v);
  }
}

// ---------------- head: per (cell, 64-row tile); atomicAdd partials to out ---------
#define H_ISSUE(S, ch) { \
  const float* src = hsrc + (ch) * 256; \
  q0_##S = *(const f32x4*)(src);      q1_##S = *(const f32x4*)(src + 4); \
  q2_##S = *(const f32x4*)(src + 8);  q3_##S = *(const f32x4*)(src + 12); \
  q4_##S = *(const f32x4*)(src + 16); q5_##S = *(const f32x4*)(src + 20); \
  q6_##S = *(const f32x4*)(src + 24); q7_##S = *(const f32x4*)(src + 28); }

#define H_WRITE(S, ch) { \
  char* dst = lbuf[(ch) & 1] + (hrow << 9); \
  *(s16x8*)(dst + ((hcb + 0)  ^ hswz)) = pack8(q0_##S, q1_##S); \
  *(s16x8*)(dst + ((hcb + 16) ^ hswz)) = pack8(q2_##S, q3_##S); \
  *(s16x8*)(dst + ((hcb + 32) ^ hswz)) = pack8(q4_##S, q5_##S); \
  *(s16x8*)(dst + ((hcb + 48) ^ hswz)) = pack8(q6_##S, q7_##S); }

#define H_SYNC { \
  asm volatile("s_waitcnt lgkmcnt(0)" ::: "memory"); \
  __builtin_amdgcn_s_barrier(); \
  asm volatile("" ::: "memory"); }

#define H_MFMA(ch) { \
  const char* bb = lbuf[(ch) & 1]; \
  s16x8 bv0 = *(const s16x8*)(bb + ((0 * 16 + lrow) << 9) + kboff); \
  s16x8 bv1 = *(const s16x8*)(bb + ((1 * 16 + lrow) << 9) + kboff); \
  s16x8 bv2 = *(const s16x8*)(bb + ((2 * 16 + lrow) << 9) + kboff); \
  s16x8 bv3 = *(const s16x8*)(bb + ((3 * 16 + lrow) << 9) + kboff); \
  s16x8 av0 = *(const s16x8*)(ap0 + (ch) * 256); \
  s16x8 av1 = *(const s16x8*)(ap1 + (ch) * 256); \
  __builtin_amdgcn_s_setprio(1); \
  acc[0][0] = __builtin_amdgcn_mfma_f32_16x16x32_bf16(av0, bv0, acc[0][0], 0, 0, 0); \
  acc[0][1] = __builtin_amdgcn_mfma_f32_16x16x32_bf16(av0, bv1, acc[0][1], 0, 0, 0); \
  acc[0][2] = __builtin_amdgcn_mfma_f32_16x16x32_bf16(av0, bv2, acc[0][2], 0, 0, 0); \
  acc[0][3] = __builtin_amdgcn_mfma_f32_16x16x32_bf16(av0, bv3, acc[0][3], 0, 0, 0); \
  acc[1][0] = __builtin_amdgcn_mfma_f32_16x16x32_bf16(av1, bv0, acc[1][0], 0, 0, 0); \
  acc[1][1] = __builtin_amdgcn_mfma_f32_16x16x32_bf16(av1, bv1, acc[1][1], 0, 0, 0); \
  acc[1][2] = __builtin_amdgcn_mfma_f32_16x16x32_bf16(av1, bv2, acc[1][2], 0, 0, 0); \
  acc[1][3] = __builtin_amdgcn_mfma_f32_16x16x32_bf16(av1, bv3, acc[1][3], 0, 0, 0); \
  __builtin_amdgcn_s_setprio(0); }

__global__ __launch_bounds__(512) void k_head(
    const int* __restrict__ cells, const u16* __restrict__ y2b,
    const float* __restrict__ L0, const float* __restrict__ O0,
    const float* __restrict__ L1, float* __restrict__ out) {
  __shared__ int slist[544];
  __shared__ int scnt;
  __shared__ float red[8][2048];      // 64 KB
  __shared__ char lbuf[2][32768];     // 64 KB
  const int tid = threadIdx.x;
  const int c = blockIdx.x >> 3, rt = blockIdx.x & 7;
  if (tid == 0) scnt = 0;
  __syncthreads();
  for (int i = tid; i < BATCH; i += 512)
    if (cells[i] == c) slist[atomicAdd(&scnt, 1)] = i;
  __syncthreads();
  const int ns = scnt;
  if (ns == 0) return;
  const int npad = (ns + 31) & ~31;
  for (int i = ns + tid; i < npad; i += 512) slist[i] = slist[0];
  __syncthreads();

  const int w = tid >> 6, l = tid & 63;
  const int lrow = l & 15;
  const int r0 = rt * 64;
  const float* L0c = L0 + ((size_t)c * N2 + r0) * N1;
  const int hrow = tid >> 3;
  const int hcb = (tid & 7) * 64;
  const int hswz = (hrow & 7) << 4;
  const float* hsrc = L0c + (size_t)hrow * N1 + (tid & 7) * 32;
  const int kboff = ((w * 64 + ((l >> 4) << 4)) ^ ((lrow & 7) << 4));

  f32x4 q0_A, q1_A, q2_A, q3_A, q4_A, q5_A, q6_A, q7_A;
  f32x4 q0_B, q1_B, q2_B, q3_B, q4_B, q5_B, q6_B, q7_B;

  for (int cb = 0; cb < npad; cb += 32) {
    const u16* ap0 = y2b + (size_t)slist[cb + lrow] * N1 + w * 32 + ((l >> 4) << 3);
    const u16* ap1 = y2b + (size_t)slist[cb + 16 + lrow] * N1 + w * 32 + ((l >> 4) << 3);
    f32x4 acc[2][4] = {};
    H_ISSUE(A, 0)
    H_WRITE(A, 0)
    H_ISSUE(B, 1)
    H_SYNC
    H_MFMA(0)
    H_WRITE(B, 1)
    H_ISSUE(A, 2)
    H_SYNC
    H_MFMA(1)
    H_WRITE(A, 2)
    H_ISSUE(B, 3)
    H_SYNC
    H_MFMA(2)
    H_WRITE(B, 3)
    H_SYNC
    H_MFMA(3)

    __syncthreads();
#pragma unroll
    for (int h = 0; h < 2; ++h)
#pragma unroll
      for (int fb = 0; fb < 4; ++fb)
#pragma unroll
        for (int r = 0; r < 4; ++r) {
          const int s0 = h * 16 + (l >> 4) * 4 + r;
          red[w][s0 * 64 + fb * 16 + lrow] = acc[h][fb][r];
        }
    __syncthreads();
    {
      const int s = tid >> 4;
      const int rq = (tid & 15) * 4;
      if (cb + s < ns) {
        float p = 0.f;
#pragma unroll
        for (int j = 0; j < 4; ++j) {
          const int r = rq + j, e = s * 64 + r;
          float v = red[0][e] + red[1][e] + red[2][e] + red[3][e] +
                    red[4][e] + red[5][e] + red[6][e] + red[7][e] +
                    O0[(size_t)c * N2 + r0 + r];
          v = v > 0.f ? v : 0.f;
          p += v * L1[(size_t)c * N2 + r0 + r];
        }
#pragma unroll
        for (int off = 8; off; off >>= 1) p += __shfl_xor(p, off, 16);
        if ((tid & 15) == 0) atomicAdd(&out[slist[cb + s]], p);
      }
    }
  }
}

// ---------------- launch ----------------
extern "C" void kernel_launch(void* const* d_in, const int* in_sizes, int n_in,
                              void* d_out, int out_size, void* d_ws, size_t ws_size,
                              hipStream_t stream) {
  const int*   pairs  = (const int*)d_in[0];
  const int*   cells  = (const int*)d_in[1];
  const float* attrs  = (const float*)d_in[2];
  const float* h_drug = (const float*)d_in[3];
  const float* W0     = (const float*)d_in[4];
  const float* b0     = (const float*)d_in[5];
  const float* W1     = (const float*)d_in[6];
  const float* b1     = (const float*)d_in[7];
  const float* L0     = (const float*)d_in[8];
  const float* O0     = (const float*)d_in[9];
  const float* L1     = (const float*)d_in[10];
  const float* O1     = (const float*)d_in[11];
  float* out = (float*)d_out;

  char* ws = (char*)d_ws;
  u16*   xb  = (u16*)(ws);                 // 2 MB  512x2048 bf16
  u16*   y1b = (u16*)(ws + (2u << 20));    // 2 MB  512x2048 bf16
  u16*   y2b = (u16*)(ws + (4u << 20));    // 1 MB  512x1024 bf16
  float* P   = (float*)(ws + (5u << 20));  // 8 MB  2x512x2048 f32 partials

  k_gather<<<BATCH, 256, 0, stream>>>(pairs, attrs, h_drug, xb, cells, O1, out);
  k_gemm1<<<512, 256, 0, stream>>>(xb, W0, P);
  k_red1<<<512, 256, 0, stream>>>(P, b0, y1b);
  k_gemm2<<<512, 256, 0, stream>>>(y1b, W1, b1, y2b);
  k_head<<<256, 512, 0, stream>>>(cells, y2b, L0, O0, L1, out);
}